// Round 1
// baseline (536.145 us; speedup 1.0000x reference)
//
#include <hip/hip_runtime.h>
#include <hip/hip_bf16.h>

#define N_NODES 100000
#define N_EDGES 1000000

typedef __bf16 bf16x8 __attribute__((ext_vector_type(8)));
typedef float  f32x4  __attribute__((ext_vector_type(4)));

#define MFMA(a, b, c) __builtin_amdgcn_mfma_f32_16x16x32_bf16((a), (b), (c), 0, 0, 0)

__device__ __forceinline__ float sigmoid_f(float x) { return 1.f / (1.f + __expf(-x)); }
__device__ __forceinline__ float tanh_f(float x) {
    float cx = fminf(fmaxf(x, -30.f), 30.f);
    float e = __expf(-2.f * cx);
    return (1.f - e) / (1.f + e);
}

// ---------------------------------------------------------------------------
// P = nf @ W1[:, 0:64]^T + b1   (bf16 out)
// Q = nf @ W1[:, 64:128]^T      (bf16 out)
// ---------------------------------------------------------------------------
__global__ __launch_bounds__(256) void pq_kernel(
    const float* __restrict__ nf, const float* __restrict__ W1,
    const float* __restrict__ b1,
    __bf16* __restrict__ Pb, __bf16* __restrict__ Qb)
{
    const int lane = threadIdx.x & 63;
    const int r = lane & 15, g = lane >> 4;

    // B-frags: B[k][n] = W1[n][k] (+64 for Q part). n = nt*16+r, k = kk*32+g*8+j
    bf16x8 Bs[4][2], Bd[4][2];
    #pragma unroll
    for (int nt = 0; nt < 4; ++nt)
        #pragma unroll
        for (int kk = 0; kk < 2; ++kk) {
            const float* ws = &W1[(nt * 16 + r) * 160 + kk * 32 + g * 8];
            const float* wd = ws + 64;
            f32x4 s0 = *(const f32x4*)ws, s1 = *(const f32x4*)(ws + 4);
            f32x4 d0 = *(const f32x4*)wd, d1 = *(const f32x4*)(wd + 4);
            #pragma unroll
            for (int j = 0; j < 4; ++j) {
                Bs[nt][kk][j] = (__bf16)s0[j]; Bs[nt][kk][j + 4] = (__bf16)s1[j];
                Bd[nt][kk][j] = (__bf16)d0[j]; Bd[nt][kk][j + 4] = (__bf16)d1[j];
            }
        }
    float b1v[4];
    #pragma unroll
    for (int nt = 0; nt < 4; ++nt) b1v[nt] = b1[nt * 16 + r];

    const int wid = blockIdx.x * (blockDim.x >> 6) + (threadIdx.x >> 6);
    const int nW  = gridDim.x * (blockDim.x >> 6);
    for (int t = wid; t < N_NODES / 16; t += nW) {
        const int base = t * 16;
        bf16x8 A[2];
        #pragma unroll
        for (int kk = 0; kk < 2; ++kk) {
            const float* p = &nf[(size_t)(base + r) * 64 + kk * 32 + g * 8];
            f32x4 v0 = *(const f32x4*)p, v1 = *(const f32x4*)(p + 4);
            #pragma unroll
            for (int j = 0; j < 4; ++j) { A[kk][j] = (__bf16)v0[j]; A[kk][j + 4] = (__bf16)v1[j]; }
        }
        f32x4 accP[4] = {}, accQ[4] = {};
        #pragma unroll
        for (int nt = 0; nt < 4; ++nt)
            #pragma unroll
            for (int kk = 0; kk < 2; ++kk) {
                accP[nt] = MFMA(A[kk], Bs[nt][kk], accP[nt]);
                accQ[nt] = MFMA(A[kk], Bd[nt][kk], accQ[nt]);
            }
        #pragma unroll
        for (int nt = 0; nt < 4; ++nt)
            #pragma unroll
            for (int rr = 0; rr < 4; ++rr) {
                const int node = base + g * 4 + rr;
                const int col  = nt * 16 + r;
                Pb[(size_t)node * 64 + col] = (__bf16)(accP[nt][rr] + b1v[nt]);
                Qb[(size_t)node * 64 + col] = (__bf16)accQ[nt][rr];
            }
    }
}

// ---------------------------------------------------------------------------
// Edge kernel: per 16-edge wave tile:
//   T = ef @ W1[:,128:160]^T (MFMA, K=32) -> LDS
//   h = relu(P[src] + Q[dst] + T)  (rebuilt directly in A-frag layout)
//   m = h @ W2^T  (MFMA, K=64);  atomicAdd(agg[dst], m + b2)
// ---------------------------------------------------------------------------
#define LDH 68   // 16-row LDS stride: 68 % 32 = 4 -> uniform bank use, 16B aligned
__global__ __launch_bounds__(256) void edge_kernel(
    const int* __restrict__ ei, const float* __restrict__ ef,
    const float* __restrict__ W1, const float* __restrict__ W2,
    const float* __restrict__ b2,
    const __bf16* __restrict__ Pb, const __bf16* __restrict__ Qb,
    float* __restrict__ agg)
{
    __shared__ float lds_h[4][16 * LDH];
    const int lane = threadIdx.x & 63;
    const int r = lane & 15, g = lane >> 4;
    float* hb = lds_h[threadIdx.x >> 6];
    const int* srcI = ei;
    const int* dstI = ei + N_EDGES;

    // W1 edge-part B-frags (cols 128..159, K=32)
    bf16x8 Be[4];
    #pragma unroll
    for (int nt = 0; nt < 4; ++nt) {
        const float* w = &W1[(nt * 16 + r) * 160 + 128 + g * 8];
        f32x4 w0 = *(const f32x4*)w, w1 = *(const f32x4*)(w + 4);
        #pragma unroll
        for (int j = 0; j < 4; ++j) { Be[nt][j] = (__bf16)w0[j]; Be[nt][j + 4] = (__bf16)w1[j]; }
    }
    // W2 B-frags (K=64)
    bf16x8 B2[4][2];
    #pragma unroll
    for (int nt = 0; nt < 4; ++nt)
        #pragma unroll
        for (int kk = 0; kk < 2; ++kk) {
            const float* w = &W2[(nt * 16 + r) * 64 + kk * 32 + g * 8];
            f32x4 w0 = *(const f32x4*)w, w1 = *(const f32x4*)(w + 4);
            #pragma unroll
            for (int j = 0; j < 4; ++j) { B2[nt][kk][j] = (__bf16)w0[j]; B2[nt][kk][j + 4] = (__bf16)w1[j]; }
        }
    float b2v[4];
    #pragma unroll
    for (int nt = 0; nt < 4; ++nt) b2v[nt] = b2[nt * 16 + r];

    const int wid = blockIdx.x * (blockDim.x >> 6) + (threadIdx.x >> 6);
    const int nW  = gridDim.x * (blockDim.x >> 6);
    for (int t = wid; t < N_EDGES / 16; t += nW) {
        const int base = t * 16;
        const int er = base + r;              // this lane's A-frag edge row
        const int es = srcI[er], ed = dstI[er];

        // layer-1 edge part: A-frag from edge_features (K=32, one k-step)
        bf16x8 Ae;
        {
            const float* p = &ef[(size_t)er * 32 + g * 8];
            f32x4 v0 = *(const f32x4*)p, v1 = *(const f32x4*)(p + 4);
            #pragma unroll
            for (int j = 0; j < 4; ++j) { Ae[j] = (__bf16)v0[j]; Ae[j + 4] = (__bf16)v1[j]; }
        }
        f32x4 accT[4] = {};
        #pragma unroll
        for (int nt = 0; nt < 4; ++nt) accT[nt] = MFMA(Ae, Be[nt], accT[nt]);

        // C-layout -> LDS so we can re-read in A-layout (per-wave region, no barrier)
        #pragma unroll
        for (int nt = 0; nt < 4; ++nt)
            #pragma unroll
            for (int rr = 0; rr < 4; ++rr)
                hb[(g * 4 + rr) * LDH + nt * 16 + r] = accT[nt][rr];

        // build layer-2 A-frags: relu(P[src] + Q[dst] + T)
        bf16x8 A2[2];
        #pragma unroll
        for (int kk = 0; kk < 2; ++kk) {
            const int k = kk * 32 + g * 8;
            const float* hp = &hb[r * LDH + k];
            f32x4 h0 = *(const f32x4*)hp, h1 = *(const f32x4*)(hp + 4);
            bf16x8 p8 = *(const bf16x8*)(Pb + (size_t)es * 64 + k);
            bf16x8 q8 = *(const bf16x8*)(Qb + (size_t)ed * 64 + k);
            #pragma unroll
            for (int j = 0; j < 4; ++j) {
                A2[kk][j]     = (__bf16)fmaxf(h0[j] + (float)p8[j]     + (float)q8[j],     0.f);
                A2[kk][j + 4] = (__bf16)fmaxf(h1[j] + (float)p8[j + 4] + (float)q8[j + 4], 0.f);
            }
        }
        f32x4 accM[4] = {};
        #pragma unroll
        for (int nt = 0; nt < 4; ++nt)
            #pragma unroll
            for (int kk = 0; kk < 2; ++kk)
                accM[nt] = MFMA(A2[kk], B2[nt][kk], accM[nt]);

        // scatter: C-layout row = g*4+rr -> edge base+g*4+rr; 16 lanes hit 16
        // consecutive floats of one agg row (coalesced 64B atomic chunks)
        int4 d4 = *(const int4*)(dstI + base + g * 4);
        const int* dd = (const int*)&d4;
        #pragma unroll
        for (int rr = 0; rr < 4; ++rr) {
            float* dp = agg + (size_t)dd[rr] * 64;
            #pragma unroll
            for (int nt = 0; nt < 4; ++nt)
                atomicAdd(dp + nt * 16 + r, accM[nt][rr] + b2v[nt]);
        }
    }
}

// ---------------------------------------------------------------------------
// GRU: gi = agg @ w_ih^T + b_ih ; gh = nf @ w_hh^T + b_hh (split-bf16 A for
// accuracy); gates in fp32; out = (1-z)*n + z*h
// ---------------------------------------------------------------------------
__global__ __launch_bounds__(256) void gru_kernel(
    const float* __restrict__ nf, const float* __restrict__ agg,
    const float* __restrict__ w_ih, const float* __restrict__ w_hh,
    const float* __restrict__ b_ih, const float* __restrict__ b_hh,
    float* __restrict__ out)
{
    const int lane = threadIdx.x & 63;
    const int r = lane & 15, g = lane >> 4;
    const int wid = blockIdx.x * (blockDim.x >> 6) + (threadIdx.x >> 6);
    const int nW  = gridDim.x * (blockDim.x >> 6);

    float br[4], bz[4], bin_[4], bhn_[4];
    #pragma unroll
    for (int nt = 0; nt < 4; ++nt) {
        const int d = nt * 16 + r;
        br[nt]   = b_ih[d] + b_hh[d];
        bz[nt]   = b_ih[64 + d] + b_hh[64 + d];
        bin_[nt] = b_ih[128 + d];
        bhn_[nt] = b_hh[128 + d];
    }

    for (int t = wid; t < N_NODES / 16; t += nW) {
        const int base = t * 16;
        // split-precision A-frags: x = hi + lo (two bf16 MFMAs ~ fp24 accuracy)
        bf16x8 aaH[2], aaL[2], ahH[2], ahL[2];
        #pragma unroll
        for (int kk = 0; kk < 2; ++kk) {
            const float* pa = &agg[(size_t)(base + r) * 64 + kk * 32 + g * 8];
            const float* ph = &nf [(size_t)(base + r) * 64 + kk * 32 + g * 8];
            f32x4 a0 = *(const f32x4*)pa, a1 = *(const f32x4*)(pa + 4);
            f32x4 h0 = *(const f32x4*)ph, h1 = *(const f32x4*)(ph + 4);
            #pragma unroll
            for (int j = 0; j < 4; ++j) {
                float av0 = a0[j], av1 = a1[j], hv0 = h0[j], hv1 = h1[j];
                __bf16 x;
                x = (__bf16)av0; aaH[kk][j]     = x; aaL[kk][j]     = (__bf16)(av0 - (float)x);
                x = (__bf16)av1; aaH[kk][j + 4] = x; aaL[kk][j + 4] = (__bf16)(av1 - (float)x);
                x = (__bf16)hv0; ahH[kk][j]     = x; ahL[kk][j]     = (__bf16)(hv0 - (float)x);
                x = (__bf16)hv1; ahH[kk][j + 4] = x; ahL[kk][j + 4] = (__bf16)(hv1 - (float)x);
            }
        }

        f32x4 accR[4] = {}, accZ[4] = {}, accIN[4] = {}, accHN[4] = {};
        #pragma unroll
        for (int c = 0; c < 3; ++c) {
            bf16x8 Bi[4][2], Bh[4][2];
            #pragma unroll
            for (int nt = 0; nt < 4; ++nt)
                #pragma unroll
                for (int kk = 0; kk < 2; ++kk) {
                    const float* wi = &w_ih[(size_t)(c * 64 + nt * 16 + r) * 64 + kk * 32 + g * 8];
                    const float* wh = &w_hh[(size_t)(c * 64 + nt * 16 + r) * 64 + kk * 32 + g * 8];
                    f32x4 i0 = *(const f32x4*)wi, i1 = *(const f32x4*)(wi + 4);
                    f32x4 h0 = *(const f32x4*)wh, h1 = *(const f32x4*)(wh + 4);
                    #pragma unroll
                    for (int j = 0; j < 4; ++j) {
                        Bi[nt][kk][j] = (__bf16)i0[j]; Bi[nt][kk][j + 4] = (__bf16)i1[j];
                        Bh[nt][kk][j] = (__bf16)h0[j]; Bh[nt][kk][j + 4] = (__bf16)h1[j];
                    }
                }
            #pragma unroll
            for (int nt = 0; nt < 4; ++nt) {
                f32x4 ai = {}, ah = {};
                #pragma unroll
                for (int kk = 0; kk < 2; ++kk) {
                    ai = MFMA(aaH[kk], Bi[nt][kk], ai);
                    ai = MFMA(aaL[kk], Bi[nt][kk], ai);
                    ah = MFMA(ahH[kk], Bh[nt][kk], ah);
                    ah = MFMA(ahL[kk], Bh[nt][kk], ah);
                }
                if (c == 0)      accR[nt] = ai + ah;
                else if (c == 1) accZ[nt] = ai + ah;
                else             { accIN[nt] = ai; accHN[nt] = ah; }
            }
        }
        #pragma unroll
        for (int nt = 0; nt < 4; ++nt)
            #pragma unroll
            for (int rr = 0; rr < 4; ++rr) {
                const int node = base + g * 4 + rr;
                const int d    = nt * 16 + r;
                float rg = sigmoid_f(accR[nt][rr] + br[nt]);
                float zg = sigmoid_f(accZ[nt][rr] + bz[nt]);
                float ng = tanh_f(accIN[nt][rr] + bin_[nt] + rg * (accHN[nt][rr] + bhn_[nt]));
                float hv = nf[(size_t)node * 64 + d];
                out[(size_t)node * 64 + d] = (1.f - zg) * ng + zg * hv;
            }
    }
}

extern "C" void kernel_launch(void* const* d_in, const int* in_sizes, int n_in,
                              void* d_out, int out_size, void* d_ws, size_t ws_size,
                              hipStream_t stream) {
    const float* nf  = (const float*)d_in[0];
    const int*   ei  = (const int*)  d_in[1];
    const float* ef  = (const float*)d_in[2];
    const float* W1  = (const float*)d_in[3];
    const float* b1  = (const float*)d_in[4];
    const float* W2  = (const float*)d_in[5];
    const float* b2  = (const float*)d_in[6];
    const float* wih = (const float*)d_in[7];
    const float* whh = (const float*)d_in[8];
    const float* bih = (const float*)d_in[9];
    const float* bhh = (const float*)d_in[10];
    float* out = (float*)d_out;

    char* ws = (char*)d_ws;
    const size_t aggBytes = (size_t)N_NODES * 64 * 4;   // 25.6 MB
    const size_t pqBytes  = (size_t)N_NODES * 64 * 2;   // 12.8 MB each
    float*  agg = (float*)ws;
    __bf16* Pb  = (__bf16*)(ws + aggBytes);
    __bf16* Qb  = (__bf16*)(ws + aggBytes + pqBytes);

    hipMemsetAsync(agg, 0, aggBytes, stream);
    pq_kernel<<<1563, 256, 0, stream>>>(nf, W1, b1, Pb, Qb);
    edge_kernel<<<2048, 256, 0, stream>>>(ei, ef, W1, W2, b2, Pb, Qb, agg);
    gru_kernel<<<1563, 256, 0, stream>>>(nf, agg, wih, whh, bih, bhh, out);
}